// Round 1
// baseline (120.742 us; speedup 1.0000x reference)
//
#include <hip/hip_runtime.h>
#include <math.h>

// PointsGeneration: elementwise sigmoid + threshold-gated regression concat.
// Input planes (all fp32, [1,C,2048,2048] -> C planes of HW):
//   d_in[0] score_text [1], d_in[1] score_head [1], d_in[2] score_tail [1],
//   d_in[3] score_bond [1], d_in[4] reg_head [4], d_in[5] reg_tail [4],
//   d_in[6] reg_bond [4]
// Output: [1,16,H,W] fp32 = 16 planes of HW:
//   ch 0..3:  sigmoid(score_text/head/tail/bond)
//   ch 4..7:  reg_head * (m_text & s_head>0.5)
//   ch 8..11: reg_tail * (m_text & s_tail>0.5)
//   ch12..15: reg_bond * (s_bond>0.5)
// where m_text = s_text > 0.45 (on the sigmoid values, fp32).

static __device__ __forceinline__ float sigf(float x) {
    // Accurate fp32 sigmoid (expf, not __expf): mask comparisons sit on the
    // sigmoid value, so we want to match the numpy fp32 reference as closely
    // as possible to avoid threshold flips.
    return 1.0f / (1.0f + expf(-x));
}

__global__ __launch_bounds__(256) void points_gen_kernel(
    const float* __restrict__ p_text,
    const float* __restrict__ p_head,
    const float* __restrict__ p_tail,
    const float* __restrict__ p_bond,
    const float* __restrict__ p_rh,
    const float* __restrict__ p_rt,
    const float* __restrict__ p_rb,
    float* __restrict__ out)
{
    constexpr int N = 2048 * 2048;            // pixels per plane
    const int t = blockIdx.x * blockDim.x + threadIdx.x;  // 0 .. N/4-1
    const int i = t * 4;                      // pixel index (float4 granule)

    // ---- score planes: load, sigmoid, masks, store ----
    float4 ft = *reinterpret_cast<const float4*>(p_text + i);
    float4 fh = *reinterpret_cast<const float4*>(p_head + i);
    float4 fl = *reinterpret_cast<const float4*>(p_tail + i);
    float4 fb = *reinterpret_cast<const float4*>(p_bond + i);

    float st[4] = {ft.x, ft.y, ft.z, ft.w};
    float sh[4] = {fh.x, fh.y, fh.z, fh.w};
    float sl[4] = {fl.x, fl.y, fl.z, fl.w};
    float sb[4] = {fb.x, fb.y, fb.z, fb.w};

    float mh[4], ml[4], mb[4];
#pragma unroll
    for (int k = 0; k < 4; ++k) {
        st[k] = sigf(st[k]);
        sh[k] = sigf(sh[k]);
        sl[k] = sigf(sl[k]);
        sb[k] = sigf(sb[k]);
        const float mt = (st[k] > 0.45f) ? 1.0f : 0.0f;
        mh[k] = (sh[k] > 0.5f) ? mt : 0.0f;
        ml[k] = (sl[k] > 0.5f) ? mt : 0.0f;
        mb[k] = (sb[k] > 0.5f) ? 1.0f : 0.0f;
    }

    *reinterpret_cast<float4*>(out + 0 * N + i) = make_float4(st[0], st[1], st[2], st[3]);
    *reinterpret_cast<float4*>(out + 1 * N + i) = make_float4(sh[0], sh[1], sh[2], sh[3]);
    *reinterpret_cast<float4*>(out + 2 * N + i) = make_float4(sl[0], sl[1], sl[2], sl[3]);
    *reinterpret_cast<float4*>(out + 3 * N + i) = make_float4(sb[0], sb[1], sb[2], sb[3]);

    // ---- gated regression planes ----
#pragma unroll
    for (int c = 0; c < 4; ++c) {
        float4 v = *reinterpret_cast<const float4*>(p_rh + c * N + i);
        v.x *= mh[0]; v.y *= mh[1]; v.z *= mh[2]; v.w *= mh[3];
        *reinterpret_cast<float4*>(out + (4 + c) * N + i) = v;
    }
#pragma unroll
    for (int c = 0; c < 4; ++c) {
        float4 v = *reinterpret_cast<const float4*>(p_rt + c * N + i);
        v.x *= ml[0]; v.y *= ml[1]; v.z *= ml[2]; v.w *= ml[3];
        *reinterpret_cast<float4*>(out + (8 + c) * N + i) = v;
    }
#pragma unroll
    for (int c = 0; c < 4; ++c) {
        float4 v = *reinterpret_cast<const float4*>(p_rb + c * N + i);
        v.x *= mb[0]; v.y *= mb[1]; v.z *= mb[2]; v.w *= mb[3];
        *reinterpret_cast<float4*>(out + (12 + c) * N + i) = v;
    }
}

extern "C" void kernel_launch(void* const* d_in, const int* in_sizes, int n_in,
                              void* d_out, int out_size, void* d_ws, size_t ws_size,
                              hipStream_t stream) {
    (void)in_sizes; (void)n_in; (void)out_size; (void)d_ws; (void)ws_size;

    const float* p_text = (const float*)d_in[0];
    const float* p_head = (const float*)d_in[1];
    const float* p_tail = (const float*)d_in[2];
    const float* p_bond = (const float*)d_in[3];
    const float* p_rh   = (const float*)d_in[4];
    const float* p_rt   = (const float*)d_in[5];
    const float* p_rb   = (const float*)d_in[6];
    float* out = (float*)d_out;

    constexpr int N = 2048 * 2048;
    constexpr int threads = 256;
    constexpr int n4 = N / 4;                 // one thread per 4 pixels
    constexpr int blocks = n4 / threads;      // 4096, exact

    points_gen_kernel<<<blocks, threads, 0, stream>>>(
        p_text, p_head, p_tail, p_bond, p_rh, p_rt, p_rb, out);
}

// Round 2
// 119.990 us; speedup vs baseline: 1.0063x; 1.0063x over previous
//
#include <hip/hip_runtime.h>
#include <math.h>

// PointsGeneration: elementwise sigmoid + threshold-gated regression concat.
//
// R1 restructure: 4 block-groups (wave-uniform branch on blockIdx.x & 3):
//   g0: 4 score planes -> sigmoid -> out ch 0..3           (4 in / 4 out streams)
//   g1: text+head scores + reg_head -> gated -> ch 4..7    (6 in / 4 out)
//   g2: text+tail scores + reg_tail -> gated -> ch 8..11   (6 in / 4 out)
//   g3: bond score + reg_bond -> gated -> ch 12..15        (5 in / 4 out)
// Groups interleaved by low block bits so score-plane re-reads (g1..g3)
// hit L2/L3 while g0 streams them. Reduces per-wave stream count 28 -> <=10
// and VGPR pressure (more resident waves) vs the fused R0 kernel.

static __device__ __forceinline__ float sigf(float x) {
    // Accurate fp32 sigmoid (expf, not __expf): threshold comparisons sit on
    // the sigmoid value; match the numpy fp32 reference to avoid mask flips.
    return 1.0f / (1.0f + expf(-x));
}

static __device__ __forceinline__ float4 ld4(const float* p) {
    return *reinterpret_cast<const float4*>(p);
}
static __device__ __forceinline__ void st4(float* p, float4 v) {
    *reinterpret_cast<float4*>(p) = v;
}

__global__ __launch_bounds__(256) void points_gen_kernel(
    const float* __restrict__ p_text,
    const float* __restrict__ p_head,
    const float* __restrict__ p_tail,
    const float* __restrict__ p_bond,
    const float* __restrict__ p_rh,
    const float* __restrict__ p_rt,
    const float* __restrict__ p_rb,
    float* __restrict__ out)
{
    constexpr int N = 2048 * 2048;                 // pixels per plane
    const int bid = blockIdx.x;
    const int g = bid & 3;                         // group (wave-uniform)
    const int i = ((bid >> 2) * 256 + threadIdx.x) * 4;  // pixel index

    if (g == 0) {
        // ---- score planes: sigmoid, store ----
        float4 ft = ld4(p_text + i);
        float4 fh = ld4(p_head + i);
        float4 fl = ld4(p_tail + i);
        float4 fb = ld4(p_bond + i);
        float* t = &ft.x; float* h = &fh.x; float* l = &fl.x; float* b = &fb.x;
#pragma unroll
        for (int k = 0; k < 4; ++k) {
            t[k] = sigf(t[k]); h[k] = sigf(h[k]);
            l[k] = sigf(l[k]); b[k] = sigf(b[k]);
        }
        st4(out + 0 * N + i, ft);
        st4(out + 1 * N + i, fh);
        st4(out + 2 * N + i, fl);
        st4(out + 3 * N + i, fb);
    } else if (g == 1) {
        // ---- reg_head gated by (sig(text)>0.45) & (sig(head)>0.5) ----
        float4 ft = ld4(p_text + i);
        float4 fh = ld4(p_head + i);
        const float* t = &ft.x; const float* h = &fh.x;
        float m[4];
#pragma unroll
        for (int k = 0; k < 4; ++k) {
            const float mt = (sigf(t[k]) > 0.45f) ? 1.0f : 0.0f;
            m[k] = (sigf(h[k]) > 0.5f) ? mt : 0.0f;
        }
#pragma unroll
        for (int c = 0; c < 4; ++c) {
            float4 v = ld4(p_rh + c * N + i);
            v.x *= m[0]; v.y *= m[1]; v.z *= m[2]; v.w *= m[3];
            st4(out + (4 + c) * N + i, v);
        }
    } else if (g == 2) {
        // ---- reg_tail gated by (sig(text)>0.45) & (sig(tail)>0.5) ----
        float4 ft = ld4(p_text + i);
        float4 fl = ld4(p_tail + i);
        const float* t = &ft.x; const float* l = &fl.x;
        float m[4];
#pragma unroll
        for (int k = 0; k < 4; ++k) {
            const float mt = (sigf(t[k]) > 0.45f) ? 1.0f : 0.0f;
            m[k] = (sigf(l[k]) > 0.5f) ? mt : 0.0f;
        }
#pragma unroll
        for (int c = 0; c < 4; ++c) {
            float4 v = ld4(p_rt + c * N + i);
            v.x *= m[0]; v.y *= m[1]; v.z *= m[2]; v.w *= m[3];
            st4(out + (8 + c) * N + i, v);
        }
    } else {
        // ---- reg_bond gated by (sig(bond)>0.5) ----
        float4 fb = ld4(p_bond + i);
        const float* b = &fb.x;
        float m[4];
#pragma unroll
        for (int k = 0; k < 4; ++k) {
            m[k] = (sigf(b[k]) > 0.5f) ? 1.0f : 0.0f;
        }
#pragma unroll
        for (int c = 0; c < 4; ++c) {
            float4 v = ld4(p_rb + c * N + i);
            v.x *= m[0]; v.y *= m[1]; v.z *= m[2]; v.w *= m[3];
            st4(out + (12 + c) * N + i, v);
        }
    }
}

extern "C" void kernel_launch(void* const* d_in, const int* in_sizes, int n_in,
                              void* d_out, int out_size, void* d_ws, size_t ws_size,
                              hipStream_t stream) {
    (void)in_sizes; (void)n_in; (void)out_size; (void)d_ws; (void)ws_size;

    const float* p_text = (const float*)d_in[0];
    const float* p_head = (const float*)d_in[1];
    const float* p_tail = (const float*)d_in[2];
    const float* p_bond = (const float*)d_in[3];
    const float* p_rh   = (const float*)d_in[4];
    const float* p_rt   = (const float*)d_in[5];
    const float* p_rb   = (const float*)d_in[6];
    float* out = (float*)d_out;

    constexpr int N = 2048 * 2048;
    constexpr int threads = 256;
    constexpr int n4 = N / 4;                     // quads per plane
    constexpr int blocks_per_group = n4 / threads; // 4096
    constexpr int blocks = blocks_per_group * 4;   // 16384, groups interleaved

    points_gen_kernel<<<blocks, threads, 0, stream>>>(
        p_text, p_head, p_tail, p_bond, p_rh, p_rt, p_rb, out);
}